// Round 1
// baseline (332.047 us; speedup 1.0000x reference)
//
#include <hip/hip_runtime.h>
#include <stdint.h>

typedef __attribute__((ext_vector_type(8))) __bf16 bf16x8;
typedef __attribute__((ext_vector_type(4))) __bf16 bf16x4;
typedef __attribute__((ext_vector_type(4))) float  f32x4;

#define DEV __device__ __forceinline__

DEV void gload16(const void* g, void* l) {
  __builtin_amdgcn_global_load_lds((const __attribute__((address_space(1))) uint32_t*)g,
                                   (__attribute__((address_space(3))) uint32_t*)l,
                                   16, 0, 0);
}

DEV f32x4 mfma16(bf16x8 a, bf16x8 b, f32x4 c) {
  return __builtin_amdgcn_mfma_f32_16x16x32_bf16(a, b, c, 0, 0, 0);
}

// ---------------- workspace layout (bytes) ----------------
#define XB_OFF   0UL            // 16384 x 1088 bf16 = 35,651,584
#define Q_OFF    35651584UL     // 16384 x 512 bf16  = 16,777,216
#define K_OFF    52428800UL
#define V_OFF    69206016UL
#define VT_OFF   85983232UL     // [8][512][2048] bf16
#define WT_OFF   102760448UL    // 1536 x 1088 bf16 = 3,342,336
#define BIAS_OFF 106102784UL    // 1536 f32
#define GATE_OFF 106108928UL    // 16384 f32
// total 106,174,464 B (~101.3 MiB)

// ============ kernel 1: xb (concat, bf16) + gate ============
__global__ __launch_bounds__(256) void k_xbgate(
    const float* __restrict__ tf, const float* __restrict__ env,
    const float* __restrict__ Wg, const float* __restrict__ bg,
    __bf16* __restrict__ xb, float* __restrict__ gate) {
  const int row = blockIdx.x;     // 0..16383
  const int t   = threadIdx.x;    // 0..255
  const int b   = row >> 11;
  const float4 v  = ((const float4*)(tf + (size_t)row * 1024))[t];
  const float4 wv = ((const float4*)Wg)[t];
  float dot = v.x * wv.x + v.y * wv.y + v.z * wv.z + v.w * wv.w;
  bf16x4 o; o.x = (__bf16)v.x; o.y = (__bf16)v.y; o.z = (__bf16)v.z; o.w = (__bf16)v.w;
  *(bf16x4*)(xb + (size_t)row * 1088 + t * 4) = o;
  if (t < 16) {
    const float4 e  = ((const float4*)(env + b * 64))[t];
    const float4 we = ((const float4*)Wg)[256 + t];
    dot += e.x * we.x + e.y * we.y + e.z * we.z + e.w * we.w;
    bf16x4 oe; oe.x = (__bf16)e.x; oe.y = (__bf16)e.y; oe.z = (__bf16)e.z; oe.w = (__bf16)e.w;
    *(bf16x4*)(xb + (size_t)row * 1088 + 1024 + t * 4) = oe;
  }
  #pragma unroll
  for (int m = 1; m < 64; m <<= 1) dot += __shfl_xor(dot, m, 64);
  __shared__ float red[4];
  if ((t & 63) == 0) red[t >> 6] = dot;
  __syncthreads();
  if (t == 0) {
    const float d = red[0] + red[1] + red[2] + red[3] + bg[0];
    gate[row] = 0.03125f / (1.0f + __expf(-d));   // sigmoid * 1/sqrt(1024)
  }
}

// ============ kernel 2: Wt[n][k] = W[k][n] (bf16) + bias ============
__global__ __launch_bounds__(256) void k_wt(
    const float* __restrict__ Wq, const float* __restrict__ Wk, const float* __restrict__ Wv,
    const float* __restrict__ bq, const float* __restrict__ bk, const float* __restrict__ bv,
    __bf16* __restrict__ Wt, float* __restrict__ biasc) {
  const int n = blockIdx.x;      // 0..1535
  const int t = threadIdx.x;
  const float* W; const float* bias; int col;
  if (n < 512)       { W = Wq; bias = bq; col = n; }
  else if (n < 1024) { W = Wk; bias = bk; col = n - 512; }
  else               { W = Wv; bias = bv; col = n - 1024; }
  for (int kk = t; kk < 1088; kk += 256)
    Wt[(size_t)n * 1088 + kk] = (__bf16)W[(size_t)kk * 512 + col];
  if (t == 0) biasc[n] = bias[col];
}

// ============ kernel 3: QKV GEMM  M=16384 N=1536 K=1088 ============
// C = xb @ Wt^T ; q' gets gate/32 fold, all outputs bf16
__global__ __launch_bounds__(256, 2) void k_gemm(
    const __bf16* __restrict__ xb, const __bf16* __restrict__ Wt,
    const float* __restrict__ biasc, const float* __restrict__ gate,
    __bf16* __restrict__ q, __bf16* __restrict__ k, __bf16* __restrict__ v) {
  __shared__ alignas(16) __bf16 As[8192];   // 128 rows x 64 k (swizzled chunks)
  __shared__ alignas(16) __bf16 Bs[8192];
  const int id = blockIdx.x;
  const int xcd = id & 7, local = id >> 3;
  const int bm = xcd * 16 + (local & 15);   // 0..127
  const int bn = local >> 4;                // 0..11
  const int tid = threadIdx.x, w = tid >> 6, lane = tid & 63;
  const int g = lane >> 4, l15 = lane & 15;
  const int wm = w >> 1, wn = w & 1;
  f32x4 acc[4][4] = {};
  const char* Ab = (const char*)(xb + (size_t)bm * 128 * 1088);
  const char* Bb = (const char*)(Wt + (size_t)bn * 128 * 1088);

  for (int kt = 0; kt < 17; ++kt) {
    const int k0b = kt * 128;  // byte offset into a 2176B row
    #pragma unroll
    for (int i = 0; i < 4; ++i) {
      const int L = i * 4096 + w * 1024 + lane * 16;
      const int row = L >> 7;
      const int ch = (L >> 4) & 7;
      const int sch = ch ^ (row & 7);
      gload16(Ab + (size_t)row * 2176 + k0b + sch * 16, (char*)As + L);
      gload16(Bb + (size_t)row * 2176 + k0b + sch * 16, (char*)Bs + L);
    }
    __syncthreads();
    #pragma unroll
    for (int kk = 0; kk < 2; ++kk) {
      bf16x8 aF[4], bF[4];
      #pragma unroll
      for (int i = 0; i < 4; ++i) {
        const int rowa = wm * 64 + i * 16 + l15;
        const int cha = (kk * 4 + g) ^ (rowa & 7);
        aF[i] = *(const bf16x8*)((const char*)As + rowa * 128 + cha * 16);
        const int rowb = wn * 64 + i * 16 + l15;
        const int chb = (kk * 4 + g) ^ (rowb & 7);
        bF[i] = *(const bf16x8*)((const char*)Bs + rowb * 128 + chb * 16);
      }
      #pragma unroll
      for (int i = 0; i < 4; ++i)
        #pragma unroll
        for (int j = 0; j < 4; ++j)
          acc[i][j] = mfma16(aF[i], bF[j], acc[i][j]);
    }
    __syncthreads();
  }

  const int which = bn >> 2;  // 0=q 1=k 2=v
  __bf16* outp = (which == 0) ? q : (which == 1) ? k : v;
  const int ncolbase = bn * 128 + wn * 64 - which * 512;
  #pragma unroll
  for (int i = 0; i < 4; ++i) {
    #pragma unroll
    for (int r = 0; r < 4; ++r) {
      const int mrow = bm * 128 + wm * 64 + i * 16 + g * 4 + r;
      const float gt = (which == 0) ? gate[mrow] : 1.0f;
      #pragma unroll
      for (int j = 0; j < 4; ++j) {
        const int ncol = ncolbase + j * 16 + l15;
        float val = acc[i][j][r] + biasc[which * 512 + ncol];
        if (which == 0) val *= gt;
        outp[(size_t)mrow * 512 + ncol] = (__bf16)val;
      }
    }
  }
}

// ============ kernel 4: v [16384][512] -> vT [8][512][2048] ============
__global__ __launch_bounds__(256) void k_vtr(const __bf16* __restrict__ v,
                                             __bf16* __restrict__ vT) {
  __shared__ __bf16 tile[64][72];
  const int st = blockIdx.x, dt = blockIdx.y, b = blockIdx.z;
  const int t = threadIdx.x;
  {
    const int sl = t >> 2, dl = (t & 3) * 16;
    const __bf16* src = v + ((size_t)(b * 2048 + st * 64 + sl)) * 512 + dt * 64 + dl;
    *(bf16x8*)&tile[sl][dl]     = *(const bf16x8*)src;
    *(bf16x8*)&tile[sl][dl + 8] = *(const bf16x8*)(src + 8);
  }
  __syncthreads();
  {
    const int dl = t >> 2, sl = (t & 3) * 16;
    bf16x8 w0, w1;
    #pragma unroll
    for (int j = 0; j < 8; ++j) { w0[j] = tile[sl + j][dl]; w1[j] = tile[sl + 8 + j][dl]; }
    __bf16* dst = vT + ((size_t)(b * 512 + dt * 64 + dl)) * 2048 + st * 64 + sl;
    *(bf16x8*)dst = w0;
    *(bf16x8*)(dst + 8) = w1;
  }
}

// ============ kernel 5: flash attention ============
// grid 256: id&7 = batch (XCD-pinned), id>>3 = q-tile (64 rows). 4 waves x 16 rows.
__global__ __launch_bounds__(256, 1) void k_attn(
    const __bf16* __restrict__ q, const __bf16* __restrict__ kg,
    const __bf16* __restrict__ vT, float* __restrict__ out) {
  __shared__ alignas(16) __bf16 KV[8192];        // 16 KB shared staging (K chunk / V chunk)
  __shared__ alignas(16) __bf16 P[4][16][72];    // per-wave P buffer
  const int id = blockIdx.x;
  const int batch = id & 7, qt = id >> 3;
  const int tid = threadIdx.x, w = tid >> 6, lane = tid & 63;
  const int g = lane >> 4, l15 = lane & 15;
  const size_t qrow0 = (size_t)batch * 2048 + qt * 64 + w * 16;

  // Q fragments (gate/32 pre-folded): 16 x bf16x8
  bf16x8 qf[16];
  #pragma unroll
  for (int kk = 0; kk < 16; ++kk)
    qf[kk] = *(const bf16x8*)(q + (qrow0 + l15) * 512 + kk * 32 + g * 8);

  f32x4 o[32] = {};
  float m_r[4] = {-1e30f, -1e30f, -1e30f, -1e30f};
  float l_r[4] = {0.f, 0.f, 0.f, 0.f};

  const char* Kb = (const char*)(kg + (size_t)batch * 2048 * 512);
  const char* Vb = (const char*)(vT + (size_t)batch * 512 * 2048);

  #pragma unroll 1
  for (int it = 0; it < 32; ++it) {
    // ---- QK^T over 4 d-chunks of 128 ----
    f32x4 sc[4] = {};
    #pragma unroll
    for (int dc = 0; dc < 4; ++dc) {
      #pragma unroll
      for (int i = 0; i < 4; ++i) {
        const int L = i * 4096 + w * 1024 + lane * 16;
        const int row = L >> 8;            // key row 0..63 (256B rows)
        const int ch = (L >> 4) & 15;
        const int sch = ch ^ (row & 7);
        gload16(Kb + (size_t)(it * 64 + row) * 1024 + dc * 256 + sch * 16, (char*)KV + L);
      }
      __syncthreads();
      #pragma unroll
      for (int kk = 0; kk < 4; ++kk) {
        const bf16x8 a = qf[dc * 4 + kk];
        #pragma unroll
        for (int ns = 0; ns < 4; ++ns) {
          const int key = ns * 16 + l15;
          const int sw = (kk * 4 + g) ^ (key & 7);
          const bf16x8 bfr = *(const bf16x8*)((const char*)KV + key * 256 + sw * 16);
          sc[ns] = mfma16(a, bfr, sc[ns]);
        }
      }
      __syncthreads();
    }
    // ---- online softmax (rows = g*4+r, cols across 16-lane group) ----
    float corr[4];
    #pragma unroll
    for (int r = 0; r < 4; ++r) {
      float mx = fmaxf(fmaxf(sc[0][r], sc[1][r]), fmaxf(sc[2][r], sc[3][r]));
      mx = fmaxf(mx, __shfl_xor(mx, 1, 64));
      mx = fmaxf(mx, __shfl_xor(mx, 2, 64));
      mx = fmaxf(mx, __shfl_xor(mx, 4, 64));
      mx = fmaxf(mx, __shfl_xor(mx, 8, 64));
      const float mnew = fmaxf(m_r[r], mx);
      corr[r] = __expf(m_r[r] - mnew);
      float rs = 0.f;
      #pragma unroll
      for (int ns = 0; ns < 4; ++ns) {
        const float p = __expf(sc[ns][r] - mnew);
        rs += p;
        P[w][g * 4 + r][ns * 16 + l15] = (__bf16)p;
      }
      rs += __shfl_xor(rs, 1, 64);
      rs += __shfl_xor(rs, 2, 64);
      rs += __shfl_xor(rs, 4, 64);
      rs += __shfl_xor(rs, 8, 64);
      l_r[r] = l_r[r] * corr[r] + rs;
      m_r[r] = mnew;
    }
    #pragma unroll
    for (int n = 0; n < 32; ++n) {
      o[n][0] *= corr[0]; o[n][1] *= corr[1]; o[n][2] *= corr[2]; o[n][3] *= corr[3];
    }
    // P -> A fragments (same-wave LDS roundtrip; compiler inserts lgkmcnt)
    bf16x8 pa[2];
    #pragma unroll
    for (int kk2 = 0; kk2 < 2; ++kk2)
      pa[kk2] = *(const bf16x8*)&P[w][l15][g * 8 + kk2 * 32];
    // ---- PV over 4 d-chunks of 128 ----
    #pragma unroll
    for (int dc = 0; dc < 4; ++dc) {
      #pragma unroll
      for (int i = 0; i < 4; ++i) {
        const int L = i * 4096 + w * 1024 + lane * 16;
        const int row = L >> 7;            // dim row 0..127 (128B rows)
        const int ch = (L >> 4) & 7;
        const int sch = ch ^ (row & 7);
        gload16(Vb + (size_t)(dc * 128 + row) * 4096 + it * 128 + sch * 16, (char*)KV + L);
      }
      __syncthreads();
      #pragma unroll
      for (int ns8 = 0; ns8 < 8; ++ns8) {
        #pragma unroll
        for (int kk2 = 0; kk2 < 2; ++kk2) {
          const int dim = ns8 * 16 + l15;
          const int sw = (kk2 * 4 + g) ^ (dim & 7);
          const bf16x8 vb = *(const bf16x8*)((const char*)KV + dim * 128 + sw * 16);
          o[dc * 8 + ns8] = mfma16(pa[kk2], vb, o[dc * 8 + ns8]);
        }
      }
      __syncthreads();
    }
  }
  // ---- epilogue: O / l ----
  #pragma unroll
  for (int r = 0; r < 4; ++r) {
    const float inv = 1.0f / l_r[r];
    const size_t rowg = qrow0 + g * 4 + r;
    #pragma unroll
    for (int n = 0; n < 32; ++n)
      out[rowg * 512 + n * 16 + l15] = o[n][r] * inv;
  }
}

// ============ launcher ============
extern "C" void kernel_launch(void* const* d_in, const int* in_sizes, int n_in,
                              void* d_out, int out_size, void* d_ws, size_t ws_size,
                              hipStream_t stream) {
  const float* tf  = (const float*)d_in[0];
  const float* env = (const float*)d_in[1];
  const float* Wq  = (const float*)d_in[2];
  const float* bq  = (const float*)d_in[3];
  const float* Wk  = (const float*)d_in[4];
  const float* bk  = (const float*)d_in[5];
  const float* Wv  = (const float*)d_in[6];
  const float* bv  = (const float*)d_in[7];
  const float* Wg  = (const float*)d_in[8];
  const float* bg  = (const float*)d_in[9];
  float* out = (float*)d_out;
  char* ws = (char*)d_ws;

  __bf16* xb   = (__bf16*)(ws + XB_OFF);
  __bf16* qb   = (__bf16*)(ws + Q_OFF);
  __bf16* kb   = (__bf16*)(ws + K_OFF);
  __bf16* vb   = (__bf16*)(ws + V_OFF);
  __bf16* vT   = (__bf16*)(ws + VT_OFF);
  __bf16* Wt   = (__bf16*)(ws + WT_OFF);
  float* biasc = (float*)(ws + BIAS_OFF);
  float* gate  = (float*)(ws + GATE_OFF);

  k_xbgate<<<dim3(16384), dim3(256), 0, stream>>>(tf, env, Wg, bg, xb, gate);
  k_wt<<<dim3(1536), dim3(256), 0, stream>>>(Wq, Wk, Wv, bq, bk, bv, Wt, biasc);
  k_gemm<<<dim3(1536), dim3(256), 0, stream>>>(xb, Wt, biasc, gate, qb, kb, vb);
  k_vtr<<<dim3(32, 8, 8), dim3(256), 0, stream>>>(vb, vT);
  k_attn<<<dim3(256), dim3(256), 0, stream>>>(qb, kb, vT, out);
}